// Round 13
// baseline (463.874 us; speedup 1.0000x reference)
//
#include <hip/hip_runtime.h>
#include <math.h>

#define N_NODES  32
#define N_HEADS  4
#define HEAD_DIM 64
#define CDIM     256           // N_HEADS * HEAD_DIM == channels
#define HWPIX    9216          // 96*96
#define ROWF4    2304          // HWPIX/4 float4 per (n,c) row
#define E_BASE   512
#define E_TOT    544           // + 32 self loops
#define NEG_SLOPE 0.2f
#define XS       257           // LDS stride for x tile (conflict-free)

// ---------------------------------------------------------------------------
// Kernel 1: spatial mean pool — byte-identical to R7/R12 (at BW roofline).
// ---------------------------------------------------------------------------
__global__ __launch_bounds__(256, 4) void pool_kernel(const float* __restrict__ roi,
                                                      float* __restrict__ x) {
    const int wave = threadIdx.x >> 6, lane = threadIdx.x & 63;
    const int row = blockIdx.x * 4 + wave;            // 0..8191  (n*256+c)
    const float4* p = reinterpret_cast<const float4*>(roi) + (size_t)row * ROWF4 + lane;

    float4 A[12], B[12];
    float s = 0.f;

#pragma unroll
    for (int j = 0; j < 12; ++j) A[j] = p[j * 64];              // chunk 0 -> A
#pragma unroll
    for (int j = 0; j < 12; ++j) B[j] = p[(12 + j) * 64];       // chunk 1 -> B
#pragma unroll
    for (int j = 0; j < 12; ++j) s += (A[j].x + A[j].y) + (A[j].z + A[j].w);
#pragma unroll
    for (int j = 0; j < 12; ++j) A[j] = p[(24 + j) * 64];       // chunk 2 -> A
#pragma unroll
    for (int j = 0; j < 12; ++j) s += (B[j].x + B[j].y) + (B[j].z + B[j].w);
#pragma unroll
    for (int j = 0; j < 12; ++j) s += (A[j].x + A[j].y) + (A[j].z + A[j].w);

#pragma unroll
    for (int off = 32; off; off >>= 1) s += __shfl_down(s, off);
    if (lane == 0) x[row] = s * (1.0f / (float)HWPIX);
}

// ---------------------------------------------------------------------------
// gat body as a template: REPS=1 -> real kernel (byte-equivalent to R12);
// REPS=16 -> rocprof probe (pointer-laundered per rep so reps can't be CSE'd).
// ---------------------------------------------------------------------------
template <int REPS>
__global__ __launch_bounds__(256) void gat_kernel_t(const int* __restrict__ edge_index,
                                                    const float* __restrict__ x,
                                                    const float* __restrict__ W,
                                                    const float* __restrict__ a_src,
                                                    const float* __restrict__ a_dst,
                                                    const float* __restrict__ gat_bias,
                                                    const float* __restrict__ cls_W,
                                                    const float* __restrict__ cls_b,
                                                    float* __restrict__ out) {
    const int n = blockIdx.x;                         // dst node this block owns
    const int t = threadIdx.x;
    const int wavg = t >> 6, lane = t & 63;

    __shared__ float    xs[N_NODES * XS];             // 32,896 B
    __shared__ __align__(16) float asl[CDIM];         // a_src flat
    __shared__ __align__(16) float adl[CDIM];         // a_dst flat
    __shared__ float    was[CDIM * N_HEADS];          // W . a_src  [c][hd]
    __shared__ float    wad[CDIM * N_HEADS];          // W . a_dst  [c][hd]
    __shared__ float    als[N_NODES * N_HEADS];       // alpha_src, all nodes
    __shared__ float    adn[N_HEADS];                 // alpha_dst, own node
    __shared__ unsigned msegu[N_HEADS];
    __shared__ float    dseg[N_HEADS];
    __shared__ float    M[N_NODES * N_HEADS];         // attention row [s][hd]
    __shared__ float    y[N_HEADS * CDIM];
    __shared__ float    sv[CDIM];
    __shared__ float4   red4[N_HEADS][64];            // out_gat partials
    __shared__ float    cred[8][32];                  // classifier partials

#pragma unroll 1
    for (int rep = 0; rep < REPS; ++rep) {
        // launder a zero offset so the compiler cannot CSE/LICM across reps
        int zoff = 0;
        if (REPS > 1) asm volatile("" : "+v"(zoff));
        const float* xL   = x + zoff;
        const float* WL   = W + zoff;
        const float* clsL = cls_W + zoff;
        const int*   eL   = edge_index + zoff;

        // ---- issue ALL independent global loads up front ------------------
        float4 xv[8];
#pragma unroll
        for (int k = 0; k < 8; ++k) xv[k] = ((const float4*)xL)[t + k * 256];
        const float asr = a_src[t], adr = a_dst[t];
        const int es0 = eL[t],       ed0 = eL[E_BASE + t];
        const int es1 = eL[256 + t], ed1 = eL[E_BASE + 256 + t];
        float4 bias4 = make_float4(0.f, 0.f, 0.f, 0.f);
        if (t < 64) bias4 = ((const float4*)gat_bias)[t];
        float cb = 0.f;
        if (t < 32) cb = cls_b[t];

        // ---- LDS staging --------------------------------------------------
#pragma unroll
        for (int k = 0; k < 8; ++k) {
            const int i = (t + k * 256) * 4, s = i >> 8, c = i & 255;
            xs[s * XS + c + 0] = xv[k].x;
            xs[s * XS + c + 1] = xv[k].y;
            xs[s * XS + c + 2] = xv[k].z;
            xs[s * XS + c + 3] = xv[k].w;
        }
        asl[t] = asr;
        adl[t] = adr;
        if (t < 128) M[t] = 0.f;
        if (t < 4) { msegu[t] = 0u; dseg[t] = 0.f; }
        __syncthreads();

        // ---- Wa: thread t owns W row t (1 KB), unroll 32 ------------------
        {
            float accs[4] = {0.f, 0.f, 0.f, 0.f};
            float accd[4] = {0.f, 0.f, 0.f, 0.f};
            const float4* wr  = (const float4*)(WL + (size_t)t * CDIM);
            const float4* as4 = (const float4*)asl;
            const float4* ad4 = (const float4*)adl;
#pragma unroll 32
            for (int j = 0; j < 64; ++j) {            // j -> head j>>4
                const float4 w = wr[j], av = as4[j], dv = ad4[j];
                const int hd = j >> 4;
                accs[hd] += w.x * av.x + w.y * av.y + w.z * av.z + w.w * av.w;
                accd[hd] += w.x * dv.x + w.y * dv.y + w.z * dv.z + w.w * dv.w;
            }
#pragma unroll
            for (int hd = 0; hd < 4; ++hd) {
                was[t * 4 + hd] = accs[hd];
                wad[t * 4 + hd] = accd[hd];
            }
        }
        __syncthreads();

        // ---- alphas -------------------------------------------------------
        if (t < 132) {
            if (t < 128) {
                const int s = t >> 2, hd = t & 3;
                const float* xrow = &xs[s * XS];
                float acc = 0.f;
#pragma unroll 8
                for (int c = 0; c < CDIM; ++c) acc += xrow[c] * was[c * 4 + hd];
                als[t] = acc;
            } else {
                const int hd = t - 128;
                const float* xrow = &xs[n * XS];
                float acc = 0.f;
#pragma unroll 8
                for (int c = 0; c < CDIM; ++c) acc += xrow[c] * wad[c * 4 + hd];
                adn[hd] = acc;
            }
        }
        __syncthreads();

        // ---- pass A: segment max ------------------------------------------
        {
            const bool sl = (t < 32) && (t == n);
#pragma unroll
            for (int hd = 0; hd < 4; ++hd) {
                float best = -INFINITY;
                if (ed0 == n) {
                    float v = als[es0 * 4 + hd] + adn[hd];
                    best = fmaxf(best, (v >= 0.f) ? v : NEG_SLOPE * v);
                }
                if (ed1 == n) {
                    float v = als[es1 * 4 + hd] + adn[hd];
                    best = fmaxf(best, (v >= 0.f) ? v : NEG_SLOPE * v);
                }
                if (sl) {
                    float v = als[n * 4 + hd] + adn[hd];
                    best = fmaxf(best, (v >= 0.f) ? v : NEG_SLOPE * v);
                }
                if (best > -INFINITY) {
                    const int iv = __float_as_int(best);
                    const unsigned key = (iv < 0) ? ~(unsigned)iv
                                                  : ((unsigned)iv | 0x80000000u);
                    atomicMax(&msegu[hd], key);
                }
            }
        }
        __syncthreads();

        float mx[4];
#pragma unroll
        for (int hd = 0; hd < 4; ++hd) {
            const unsigned key = msegu[hd];
            const int im = (key & 0x80000000u) ? (int)(key & 0x7fffffffu) : (int)~key;
            mx[hd] = __int_as_float(im);
        }

        // ---- pass B: exp, denom, attention row ----------------------------
        {
            const bool sl = (t < 32) && (t == n);
#pragma unroll
            for (int hd = 0; hd < 4; ++hd) {
                if (ed0 == n) {
                    float v = als[es0 * 4 + hd] + adn[hd];
                    v = (v >= 0.f) ? v : NEG_SLOPE * v;
                    const float ex = expf(v - mx[hd]);
                    atomicAdd(&dseg[hd], ex);
                    atomicAdd(&M[es0 * 4 + hd], ex);
                }
                if (ed1 == n) {
                    float v = als[es1 * 4 + hd] + adn[hd];
                    v = (v >= 0.f) ? v : NEG_SLOPE * v;
                    const float ex = expf(v - mx[hd]);
                    atomicAdd(&dseg[hd], ex);
                    atomicAdd(&M[es1 * 4 + hd], ex);
                }
                if (sl) {
                    float v = als[n * 4 + hd] + adn[hd];
                    v = (v >= 0.f) ? v : NEG_SLOPE * v;
                    const float ex = expf(v - mx[hd]);
                    atomicAdd(&dseg[hd], ex);
                    atomicAdd(&M[n * 4 + hd], ex);
                }
            }
        }
        __syncthreads();
        if (t < 128) M[t] /= dseg[t & 3];
        __syncthreads();

        // ---- y[hd,c] = sum_s M[s,hd] * xs[s,c] ----------------------------
        {
            const int hd = wavg;
            float a0 = 0.f, a1 = 0.f, a2 = 0.f, a3 = 0.f;
#pragma unroll
            for (int s = 0; s < N_NODES; ++s) {
                const float m = M[s * 4 + hd];
                const float* xrow = &xs[s * XS + lane];
                a0 += m * xrow[0];   a1 += m * xrow[64];
                a2 += m * xrow[128]; a3 += m * xrow[192];
            }
            y[hd * CDIM + lane]       = a0;
            y[hd * CDIM + lane + 64]  = a1;
            y[hd * CDIM + lane + 128] = a2;
            y[hd * CDIM + lane + 192] = a3;
        }
        __syncthreads();

        // ---- out_gat: coalesced float4 W reads + 4-way LDS reduce ---------
        {
            const int hd = lane >> 4;
            const float* yrow = &y[hd * CDIM];
            float4 acc = make_float4(0.f, 0.f, 0.f, 0.f);
#pragma unroll 16
            for (int cc = 0; cc < 64; ++cc) {
                const int c = wavg * 64 + cc;
                const float4 w4 = ((const float4*)(WL + (size_t)c * CDIM))[lane];
                const float yv = yrow[c];
                acc.x += yv * w4.x; acc.y += yv * w4.y;
                acc.z += yv * w4.z; acc.w += yv * w4.w;
            }
            red4[wavg][lane] = acc;
        }
        __syncthreads();
        if (t < 64) {
            const float4 s0 = red4[0][t], s1 = red4[1][t];
            const float4 s2 = red4[2][t], s3 = red4[3][t];
            float v0 = s0.x + s1.x + s2.x + s3.x + bias4.x;
            float v1 = s0.y + s1.y + s2.y + s3.y + bias4.y;
            float v2 = s0.z + s1.z + s2.z + s3.z + bias4.z;
            float v3 = s0.w + s1.w + s2.w + s3.w + bias4.w;
            sv[4 * t + 0] = v0 / (1.0f + expf(-v0));
            sv[4 * t + 1] = v1 / (1.0f + expf(-v1));
            sv[4 * t + 2] = v2 / (1.0f + expf(-v2));
            sv[4 * t + 3] = v3 / (1.0f + expf(-v3));
        }
        __syncthreads();

        // ---- classifier ---------------------------------------------------
        {
            const int j = t & 31, g8 = t >> 5;
            float a = 0.f;
#pragma unroll
            for (int c0 = 0; c0 < 32; ++c0) {
                const int c = g8 * 32 + c0;
                a += sv[c] * clsL[c * 32 + j];
            }
            cred[g8][j] = a;
        }
        __syncthreads();
        if (t < 32) {
            float s2 = cb;
#pragma unroll
            for (int g2 = 0; g2 < 8; ++g2) s2 += cred[g2][t];
            out[n * 32 + t] = s2;
        }
        if (REPS > 1) __syncthreads();                // clean rep boundary
    }
}

// ---------------------------------------------------------------------------
extern "C" void kernel_launch(void* const* d_in, const int* in_sizes, int n_in,
                              void* d_out, int out_size, void* d_ws, size_t ws_size,
                              hipStream_t stream) {
    const float* roi   = (const float*)d_in[0];
    const int*   eidx  = (const int*)d_in[1];
    const float* W     = (const float*)d_in[2];
    const float* a_src = (const float*)d_in[3];
    const float* a_dst = (const float*)d_in[4];
    const float* gbias = (const float*)d_in[5];
    const float* clsW  = (const float*)d_in[6];
    const float* clsb  = (const float*)d_in[7];
    float* out = (float*)d_out;

    float* x    = (float*)d_ws;                // [8192] floats
    float* out2 = x + 8192;                    // probe scratch (inert)

    pool_kernel<<<(N_NODES * CDIM) / 4, 256, 0, stream>>>(roi, x);
    gat_kernel_t<1><<<N_NODES, 256, 0, stream>>>(eidx, x, W, a_src, a_dst,
                                                 gbias, clsW, clsb, out);
    // ---- PROBE: 16x gat body, visible in rocprof top-5 with full PMC ------
    gat_kernel_t<16><<<N_NODES, 256, 0, stream>>>(eidx, x, W, a_src, a_dst,
                                                  gbias, clsW, clsb, out2);
}